// Round 6
// baseline (29674.734 us; speedup 1.0000x reference)
//
#include <hip/hip_runtime.h>
#include <cstdint>
#include <cstddef>

typedef __attribute__((ext_vector_type(8))) short bf16x8;
typedef __attribute__((ext_vector_type(4))) float f32x4;
typedef uint16_t u16;
typedef uint32_t u32;
typedef uint64_t u64;

#define NS 4096

// ---------------- fixed workspace layout (bytes) ----------------
// Tagged h exchange: 4-deep rotation x 4 groups x [16 rows][128 col-pairs] u64
#define OFF_HX4    ((size_t)0)                        // 256 KB
#define OFF_STATE  ((size_t)262144)                   // 128 KB: c then h, f32 [64][256]
#define OFF_WHT    ((size_t)393216)                   // 512 KB
#define OFF_WXTH   (OFF_WHT   + (size_t)524288)
#define OFF_WXTL   (OFF_WXTH  + (size_t)262144)
#define OFF_WEF1H  (OFF_WXTL  + (size_t)262144)
#define OFF_WEF1L  (OFF_WEF1H + (size_t)32768)
#define OFF_WEF3H  (OFF_WEF1L + (size_t)32768)
#define OFF_WEF3L  (OFF_WEF3H + (size_t)65536)
#define OFF_CH     ((size_t)2*1024*1024)              // chunk region
// per-step: s hi/lo + x hi/lo + e1 hi/lo (6x16KB) + xw f32 (256KB) + j f32 (64KB)
#define CH_BYTES_PER_SC ((size_t)425984)

// ---------------- helpers ----------------
static __device__ __forceinline__ float bf2f(u16 u){
  union { uint32_t i; float f; } v; v.i = ((uint32_t)u) << 16; return v.f;
}
static __device__ __forceinline__ u16 f2bf(float f){
  union { float f; uint32_t u; } v; v.f = f;
  uint32_t r = v.u + 0x7fffu + ((v.u >> 16) & 1u);
  return (u16)(r >> 16);
}
static __device__ __forceinline__ float sigmoid_f(float x){
  return 1.f / (1.f + __expf(-x));
}
static __device__ __forceinline__ float tanh_f(float x){
  x = fminf(15.f, fmaxf(-15.f, x));
  float e = __expf(2.f * x);
  return 1.f - 2.f / (e + 1.f);
}
// Exchange protocol: each u64 = {tag:32 | h_col_odd:16 | h_col_even:16}.
// One relaxed agent-scope atomic per unit: data+validity arrive atomically, so
// no flags, no producer drain, no barrier. Consumers poll tag == T.
static __device__ __forceinline__ u64 agld64(const u64* p){
  return __hip_atomic_load(p, __ATOMIC_RELAXED, __HIP_MEMORY_SCOPE_AGENT);
}
static __device__ __forceinline__ void agst64(u64* p, u64 v){
  __hip_atomic_store(p, v, __ATOMIC_RELAXED, __HIP_MEMORY_SCOPE_AGENT);
}

// ---------------- K0: weight transpose/convert (hi/lo split for GEMM weights) ----------------
__global__ void k_prep(const float* __restrict__ Wh, const float* __restrict__ Wx,
                       const float* __restrict__ Wef1, const float* __restrict__ Wef3,
                       u16* __restrict__ WhT,
                       u16* __restrict__ WxTh, u16* __restrict__ WxTl,
                       u16* __restrict__ Wef1h, u16* __restrict__ Wef1l,
                       u16* __restrict__ Wef3h, u16* __restrict__ Wef3l){
  int idx = blockIdx.x*256 + threadIdx.x;
  if (idx < 262144){ int n = idx>>8, k = idx&255; WhT[idx] = f2bf(Wh[k*1024+n]); return; }
  idx -= 262144;
  if (idx < 131072){
    int n = idx>>7, k = idx&127; float w = Wx[k*1024+n];
    u16 h = f2bf(w); WxTh[idx] = h; WxTl[idx] = f2bf(w - bf2f(h)); return;
  }
  idx -= 131072;
  if (idx < 16384){
    int n = idx>>7, k = idx&127; float w = Wef1[k*128+n];
    u16 h = f2bf(w); Wef1h[idx] = h; Wef1l[idx] = f2bf(w - bf2f(h)); return;
  }
  idx -= 16384;
  if (idx < 32768){
    int n = idx>>7, k = idx&127; float w = Wef3[k*256+n];
    u16 h = f2bf(w); Wef3h[idx] = h; Wef3l[idx] = f2bf(w - bf2f(h)); return;
  }
}

// seed hX4 buffer[3] with h0, tag 0  (64 rows x 128 pairs)
__global__ void k_seed(const float* __restrict__ h0, u64* __restrict__ hX4){
  int idx = blockIdx.x*256 + threadIdx.x;   // 0..8191
  int gr = idx >> 7, p = idx & 127;
  u16 he = f2bf(h0[(size_t)gr*256 + 2*p]);
  u16 ho = f2bf(h0[(size_t)gr*256 + 2*p + 1]);
  int g = gr >> 4, r = gr & 15;
  hX4[((size_t)(3*4 + g)*16 + r)*128 + p] = (u64)he | ((u64)ho << 16);  // tag 0
}

// ---------------- K1: embedding (chunked): rows m = sc*64 + b, hi/lo outputs ----------------
__global__ __launch_bounds__(256) void k_embed(
    const float* __restrict__ event, const float* __restrict__ vc, const float* __restrict__ vn,
    const float* __restrict__ Ve, const float* __restrict__ Vc, const float* __restrict__ Vn,
    u16* __restrict__ sHi, u16* __restrict__ sLo,
    u16* __restrict__ xHi, u16* __restrict__ xLo, int c0){
  __shared__ float VeL[64*128];
  __shared__ float VcL[32*128];
  __shared__ float VnL[16*128];
  __shared__ float evL[16*64];
  __shared__ float vcL[16*32];
  __shared__ float vnL[16*16];
  const int tid = threadIdx.x;
  const int sc = blockIdx.x >> 2;
  const int b0 = (blockIdx.x & 3) * 16;
  const int ss = c0 + sc;
  for (int i = tid; i < 64*128; i += 256) VeL[i] = Ve[i];
  for (int i = tid; i < 32*128; i += 256) VcL[i] = Vc[i];
  for (int i = tid; i < 16*128; i += 256) VnL[i] = Vn[i];
  for (int i = tid; i < 16*64; i += 256)
    evL[i] = event[((size_t)(b0 + (i>>6))*4096 + ss)*64 + (i&63)];
  for (int i = tid; i < 16*32; i += 256)
    vcL[i] = vc[((size_t)(b0 + (i>>5))*4096 + ss)*32 + (i&31)];
  for (int i = tid; i < 16*16; i += 256)
    vnL[i] = vn[((size_t)(b0 + (i>>4))*4096 + ss)*16 + (i&15)];
  __syncthreads();
  const int n = tid & 127, half = tid >> 7;
  for (int r = half; r < 16; r += 2){
    float sd = 0.f, cd = 0.f, nd = 0.f;
    #pragma unroll 8
    for (int k = 0; k < 64; ++k) sd = fmaf(evL[r*64+k], VeL[k*128+n], sd);
    #pragma unroll 8
    for (int k = 0; k < 32; ++k) cd = fmaf(vcL[r*32+k], VcL[k*128+n], cd);
    #pragma unroll 8
    for (int k = 0; k < 16; ++k) nd = fmaf(vnL[r*16+k], VnL[k*128+n], nd);
    float x = sd + 2.f*(cd + tanh_f(nd));
    size_t o = ((size_t)sc*64 + b0 + r)*128 + n;
    u16 sh = f2bf(sd); sHi[o] = sh; sLo[o] = f2bf(sd - bf2f(sh));
    u16 xh = f2bf(x);  xHi[o] = xh; xLo[o] = f2bf(x  - bf2f(xh));
  }
}

// ---------------- K2: split-bf16 ("bf16x3") MFMA GEMM, K=128, act+bias epilogue ----------------
// OUTKIND 0: f32 C[m][N]   1: f32 xw gate-interleaved [m][hid][gate]   2: hi/lo bf16 planes [m][N]
template<int ACT, int OUTKIND, int NTILES>
__global__ __launch_bounds__(256) void k_gemm(
    const u16* __restrict__ Ahi, const u16* __restrict__ Alo,
    const u16* __restrict__ BTh, const u16* __restrict__ BTl,
    const float* __restrict__ bias,
    float* __restrict__ CoutF, u16* __restrict__ CoutHi, u16* __restrict__ CoutLo){
  __shared__ u16 aLh[4][16*136];
  __shared__ u16 aLl[4][16*136];
  const int tid = threadIdx.x, lane = tid & 63, w = tid >> 6;
  const int c15 = lane & 15, q4 = lane >> 4;
  const size_t mbase = (size_t)blockIdx.x*64 + (size_t)w*16;
  const u16* Aph = Ahi + mbase*128;
  const u16* Apl = Alo + mbase*128;
  #pragma unroll
  for (int i = 0; i < 4; ++i){
    int row = q4 + i*4;
    *(bf16x8*)(&aLh[w][row*136 + c15*8]) = *(const bf16x8*)(Aph + row*128 + c15*8);
    *(bf16x8*)(&aLl[w][row*136 + c15*8]) = *(const bf16x8*)(Apl + row*128 + c15*8);
  }
  __syncthreads();
  bf16x8 ah[4], al[4];
  #pragma unroll
  for (int q = 0; q < 4; ++q){
    ah[q] = *(const bf16x8*)(&aLh[w][c15*136 + q*32 + q4*8]);
    al[q] = *(const bf16x8*)(&aLl[w][c15*136 + q*32 + q4*8]);
  }
  const u16* Bph = BTh + c15*128 + q4*8;
  const u16* Bpl = BTl + c15*128 + q4*8;

  bf16x8 bh[4], bl[4], bhn[4], bln[4];
  #pragma unroll
  for (int q = 0; q < 4; ++q){ bh[q] = *(const bf16x8*)(Bph + q*32); bl[q] = *(const bf16x8*)(Bpl + q*32); }

  for (int nt = 0; nt < NTILES; ++nt){
    if (nt + 1 < NTILES){
      #pragma unroll
      for (int q = 0; q < 4; ++q){
        bhn[q] = *(const bf16x8*)(Bph + (nt+1)*2048 + q*32);
        bln[q] = *(const bf16x8*)(Bpl + (nt+1)*2048 + q*32);
      }
    }
    f32x4 acc = (f32x4){0.f,0.f,0.f,0.f};
    #pragma unroll
    for (int q = 0; q < 4; ++q){
      acc = __builtin_amdgcn_mfma_f32_16x16x32_bf16(al[q], bh[q], acc, 0, 0, 0);
      acc = __builtin_amdgcn_mfma_f32_16x16x32_bf16(ah[q], bl[q], acc, 0, 0, 0);
      acc = __builtin_amdgcn_mfma_f32_16x16x32_bf16(ah[q], bh[q], acc, 0, 0, 0);
    }
    const int n = nt*16 + c15;
    const float bv = bias[n];
    #pragma unroll
    for (int i = 0; i < 4; ++i){
      float v = acc[i] + bv;
      if (ACT == 1) v = tanh_f(v);
      else if (ACT == 2) v = sigmoid_f(v);
      const size_t m = mbase + q4*4 + i;
      if (OUTKIND == 0){
        CoutF[m*(size_t)(NTILES*16) + n] = v;
      } else if (OUTKIND == 1){
        CoutF[m*1024 + (size_t)(n & 255)*4 + (size_t)(n >> 8)] = v;
      } else {
        size_t o = m*(size_t)(NTILES*16) + n;
        u16 hh = f2bf(v); CoutHi[o] = hh; CoutLo[o] = f2bf(v - bf2f(hh));
      }
    }
    #pragma unroll
    for (int q = 0; q < 4; ++q){ bh[q] = bhn[q]; bl[q] = bln[q]; }
  }
}

// ---------------- K3: the scan (chunked, tagged-u64 exchange, no barriers) ----------------
// 16 WGs = 4 batch-groups x 4 N-slots; each wave owns a 16x16 h tile.
// Wh slice register-resident. All A-operand h (own + partner) read via tagged
// u64 poll from MALL; 4-deep buffer rotation makes stale-overwrite impossible.
__global__ __launch_bounds__(256, 1) void k_scan(
    const u16* __restrict__ WhT, const float* __restrict__ xwG, const float* __restrict__ jG,
    const float* __restrict__ Wc, const float* __restrict__ h0, const float* __restrict__ c0in,
    const float* __restrict__ Wlin, const float* __restrict__ blin,
    u64* __restrict__ hX4, float* __restrict__ stateF,
    float* __restrict__ out, int T0, int SC, int FINAL)
{
  const int tid  = threadIdx.x;
  const int lane = tid & 63;
  const int w    = tid >> 6;
  const int g    = blockIdx.x & 3;
  const int s    = blockIdx.x >> 2;
  const int c15  = lane & 15;
  const int q4   = lane >> 4;
  const int ghid = s*64 + w*16 + c15;
  const int FIRST = (T0 == 0);

  // Wh fragments for this wave's 16 cols x 4 gates (128 VGPRs)
  bf16x8 Bf[4][8];
  {
    const u16* bp = WhT + (size_t)ghid*256 + q4*8;
    #pragma unroll
    for (int gt = 0; gt < 4; ++gt)
      #pragma unroll
      for (int q = 0; q < 8; ++q)
        Bf[gt][q] = *(const bf16x8*)(bp + (size_t)gt*65536 + q*32);
  }

  float creg[4], hreg[4];
  #pragma unroll
  for (int i = 0; i < 4; ++i){
    int r = q4*4 + i;
    if (FIRST){
      creg[i] = c0in[(size_t)(g*16 + r)*256 + ghid];
      hreg[i] = h0[(size_t)(g*16 + r)*256 + ghid];
    } else {
      creg[i] = stateF[(size_t)(g*16 + r)*256 + ghid];
      hreg[i] = stateF[16384 + (size_t)(g*16 + r)*256 + ghid];
    }
  }
  const float wc0 = Wc[ghid], wc1 = Wc[256 + ghid], wc2 = Wc[512 + ghid];

  const int P = s*32 + w*8 + (c15 >> 1);   // col-pair index this lane stores

  for (int t = 0; t < SC; ++t){
    const unsigned T = (unsigned)(T0 + t);
    const int rb = (int)((T + 3) & 3);     // read buffer: (T-1) mod 4
    const int wb = (int)(T & 3);           // write buffer: T mod 4

    // xw/j for this step: plain loads, latency hidden behind the poll
    f32x4 xq[4]; float jv[4];
    {
      const float* xwp = xwG + ((size_t)t*64 + g*16)*1024 + (size_t)ghid*4;
      const float* jp  = jG  + ((size_t)t*64 + g*16)*256 + ghid;
      #pragma unroll
      for (int i = 0; i < 4; ++i){
        int r = q4*4 + i;
        xq[i] = *(const f32x4*)(xwp + (size_t)r*1024);
        jv[i] = jp[(size_t)r*256];
      }
    }

    // ---- poll A-operand row c15 (32 tagged u64s = 256 h values) ----
    const u64* hr = hX4 + ((size_t)(rb*4 + g)*16 + c15)*128;
    u64 d[8][4];
    #pragma unroll
    for (int q = 0; q < 8; ++q)
      #pragma unroll
      for (int jj = 0; jj < 4; ++jj)
        d[q][jj] = agld64(hr + q*16 + q4*4 + jj);
    for (;;){
      bool ok = true;
      #pragma unroll
      for (int q = 0; q < 8; ++q)
        #pragma unroll
        for (int jj = 0; jj < 4; ++jj)
          ok &= ((u32)(d[q][jj] >> 32) == T);
      if (ok) break;
      #pragma unroll
      for (int q = 0; q < 8; ++q)
        #pragma unroll
        for (int jj = 0; jj < 4; ++jj)
          if ((u32)(d[q][jj] >> 32) != T)
            d[q][jj] = agld64(hr + q*16 + q4*4 + jj);
    }
    bf16x8 Af[8];
    #pragma unroll
    for (int q = 0; q < 8; ++q){
      union { u32 dd[4]; bf16x8 v; } cv;
      #pragma unroll
      for (int jj = 0; jj < 4; ++jj) cv.dd[jj] = (u32)d[q][jj];
      Af[q] = cv.v;
    }

    // ---- MFMA: gates(16x16 per gate) = h(16x256) @ Wh_tile ----
    f32x4 acc[4];
    #pragma unroll
    for (int gt = 0; gt < 4; ++gt) acc[gt] = (f32x4){0.f,0.f,0.f,0.f};
    #pragma unroll
    for (int q = 0; q < 8; ++q)
      #pragma unroll
      for (int gt = 0; gt < 4; ++gt)
        acc[gt] = __builtin_amdgcn_mfma_f32_16x16x32_bf16(Af[q], Bf[gt][q], acc[gt], 0, 0, 0);

    // ---- elementwise LSTM update (4 rows x col c15) ----
    u16 hb[4];
    #pragma unroll
    for (int i = 0; i < 4; ++i){
      float ip = acc[0][i] + xq[i][0] + creg[i]*wc0;
      float fp = acc[1][i] + xq[i][1] + creg[i]*wc1;
      float gp = acc[2][i] + xq[i][2];
      float op = acc[3][i] + xq[i][3] + creg[i]*wc2;
      float it = sigmoid_f(ip);
      float ft = sigmoid_f(fp);
      float gt = tanh_f(gp);
      float ot = sigmoid_f(op);
      float chat = ft*creg[i] + it*gt;
      float cn = creg[i] + jv[i]*(chat - creg[i]);
      float hhat = ot*tanh_f(chat);
      float hn = hreg[i] + jv[i]*(hhat - hreg[i]);
      creg[i] = cn; hreg[i] = hn;
      hb[i] = f2bf(hn);
    }

    // ---- pack col-pairs via lane^1 exchange, tagged stores ----
    u32 a = (u32)hb[0] | ((u32)hb[1] << 16);
    u32 b = (u32)hb[2] | ((u32)hb[3] << 16);
    u32 pa = (u32)__shfl_xor((int)a, 1, 64);
    u32 pb = (u32)__shfl_xor((int)b, 1, 64);
    u64* hw = hX4 + (size_t)(wb*4 + g)*2048;
    const u64 tag = ((u64)(T + 1)) << 32;
    if ((lane & 1) == 0){
      u64 v0 = tag | (u64)((a & 0xffffu) | ((pa & 0xffffu) << 16));
      u64 v1 = tag | (u64)((a >> 16) | (pa & 0xffff0000u));
      agst64(hw + (q4*4 + 0)*128 + P, v0);
      agst64(hw + (q4*4 + 1)*128 + P, v1);
    } else {
      u64 v2 = tag | (u64)((pb & 0xffffu) | ((b & 0xffffu) << 16));
      u64 v3 = tag | (u64)((pb >> 16) | (b & 0xffff0000u));
      agst64(hw + (q4*4 + 2)*128 + P, v2);
      agst64(hw + (q4*4 + 3)*128 + P, v3);
    }
  }

  // persist f32 state for next chunk (same wave reads it back next launch)
  if (!FINAL){
    #pragma unroll
    for (int i = 0; i < 4; ++i){
      int r = q4*4 + i;
      stateF[(size_t)(g*16 + r)*256 + ghid] = creg[i];
      stateF[16384 + (size_t)(g*16 + r)*256 + ghid] = hreg[i];
    }
  }

  // epilogue on final chunk: out = h_T @ Wlin + blin  (slot-0 WG per group)
  if (FINAL && s == 0){
    __shared__ float hF[16*256];
    const unsigned tgt = (unsigned)NS;     // h_T carries tag NS in buffer 3
    for (int idx = tid; idx < 2048; idx += 256){
      int r = idx >> 7, p = idx & 127;
      const u64* ap = hX4 + ((size_t)(3*4 + g)*16 + r)*128 + p;
      u64 v;
      do { v = agld64(ap); } while ((u32)(v >> 32) != tgt);
      hF[r*256 + 2*p]     = bf2f((u16)v);
      hF[r*256 + 2*p + 1] = bf2f((u16)(v >> 16));
    }
    __syncthreads();
    for (int idx = tid; idx < 1024; idx += 256){
      int r = idx >> 6, dcol = idx & 63;
      float aacc = blin[dcol];
      for (int k = 0; k < 256; ++k)
        aacc = fmaf(hF[r*256 + k], Wlin[k*64 + dcol], aacc);
      out[(size_t)(g*16 + r)*64 + dcol] = aacc;
    }
  }
}

// ---------------- host ----------------
extern "C" void kernel_launch(void* const* d_in, const int* in_sizes, int n_in,
                              void* d_out, int out_size, void* d_ws, size_t ws_size,
                              hipStream_t stream)
{
  (void)in_sizes; (void)n_in;
  const float* event = (const float*)d_in[0];
  const float* vc    = (const float*)d_in[2];
  const float* vn    = (const float*)d_in[3];
  const float* h0    = (const float*)d_in[4];
  const float* c0v   = (const float*)d_in[5];
  const float* Wx    = (const float*)d_in[6];
  const float* Wh    = (const float*)d_in[7];
  const float* Wc    = (const float*)d_in[8];
  const float* bias  = (const float*)d_in[9];
  const float* Ve    = (const float*)d_in[10];
  const float* Vc    = (const float*)d_in[11];
  const float* Vn    = (const float*)d_in[12];
  const float* Wlin  = (const float*)d_in[13];
  const float* blin  = (const float*)d_in[14];
  const float* Wef1  = (const float*)d_in[15];
  const float* bef1  = (const float*)d_in[16];
  const float* Wef3  = (const float*)d_in[17];
  const float* bef3  = (const float*)d_in[18];

  int SC = 0;
  const int cands[9] = {4096, 2048, 1024, 512, 256, 128, 64, 32, 16};
  for (int i = 0; i < 9; ++i){
    if (OFF_CH + (size_t)cands[i]*CH_BYTES_PER_SC <= ws_size){ SC = cands[i]; break; }
  }
  if (SC == 0){
    hipMemsetAsync(d_out, 0, (size_t)out_size*sizeof(float), stream);
    return;
  }
  const int C = NS / SC;

  char* ws = (char*)d_ws;
  u64*   hX4    = (u64*)(ws + OFF_HX4);
  float* stateF = (float*)(ws + OFF_STATE);
  u16* WhT   = (u16*)(ws + OFF_WHT);
  u16* WxTh  = (u16*)(ws + OFF_WXTH);
  u16* WxTl  = (u16*)(ws + OFF_WXTL);
  u16* Wef1h = (u16*)(ws + OFF_WEF1H);
  u16* Wef1l = (u16*)(ws + OFF_WEF1L);
  u16* Wef3h = (u16*)(ws + OFF_WEF3H);
  u16* Wef3l = (u16*)(ws + OFF_WEF3L);
  char* ch = ws + OFF_CH;
  u16* sHi  = (u16*)ch;
  u16* sLo  = (u16*)(ch + (size_t)SC*16384);
  u16* xHi  = (u16*)(ch + (size_t)SC*32768);
  u16* xLo  = (u16*)(ch + (size_t)SC*49152);
  u16* e1Hi = (u16*)(ch + (size_t)SC*65536);
  u16* e1Lo = (u16*)(ch + (size_t)SC*81920);
  float* xwG = (float*)(ch + (size_t)SC*98304);
  float* jG  = (float*)(ch + (size_t)SC*360448);

  k_prep<<<1728, 256, 0, stream>>>(Wh, Wx, Wef1, Wef3, WhT, WxTh, WxTl,
                                   Wef1h, Wef1l, Wef3h, Wef3l);
  k_seed<<<32, 256, 0, stream>>>(h0, hX4);

  for (int c = 0; c < C; ++c){
    const int c0 = c * SC;
    k_embed<<<SC*4, 256, 0, stream>>>(event, vc, vn, Ve, Vc, Vn, sHi, sLo, xHi, xLo, c0);
    k_gemm<0,1,64><<<SC, 256, 0, stream>>>(xHi, xLo, WxTh, WxTl, bias, xwG, nullptr, nullptr);
    k_gemm<1,2,8><<<SC, 256, 0, stream>>>(sHi, sLo, Wef1h, Wef1l, bef1, nullptr, e1Hi, e1Lo);
    k_gemm<2,0,16><<<SC, 256, 0, stream>>>(e1Hi, e1Lo, Wef3h, Wef3l, bef3, jG, nullptr, nullptr);
    k_scan<<<16, 256, 0, stream>>>(WhT, xwG, jG, Wc, h0, c0v, Wlin, blin,
                                   hX4, stateF, (float*)d_out, c0, SC, (c == C-1) ? 1 : 0);
  }
}

// Round 7
// 19465.359 us; speedup vs baseline: 1.5245x; 1.5245x over previous
//
#include <hip/hip_runtime.h>
#include <cstdint>
#include <cstddef>

typedef __attribute__((ext_vector_type(8))) short bf16x8;
typedef __attribute__((ext_vector_type(4))) float f32x4;
typedef uint16_t u16;
typedef uint32_t u32;
typedef uint64_t u64;

#define NS 4096

// ---------------- fixed workspace layout (bytes) ----------------
// Tagged h exchange, PAIR-MAJOR: 4-deep rotation x 4 groups x [128 col-pairs][16 rows] u64
#define OFF_HX4    ((size_t)0)                        // 256 KB
#define OFF_STATE  ((size_t)262144)                   // 128 KB: c then h, f32 [64][256]
#define OFF_WHT    ((size_t)393216)                   // 512 KB
#define OFF_WXTH   (OFF_WHT   + (size_t)524288)
#define OFF_WXTL   (OFF_WXTH  + (size_t)262144)
#define OFF_WEF1H  (OFF_WXTL  + (size_t)262144)
#define OFF_WEF1L  (OFF_WEF1H + (size_t)32768)
#define OFF_WEF3H  (OFF_WEF1L + (size_t)32768)
#define OFF_WEF3L  (OFF_WEF3H + (size_t)65536)
#define OFF_CH     ((size_t)2*1024*1024)              // chunk region
// per-step: s hi/lo + x hi/lo + e1 hi/lo (6x16KB) + xw f32 (256KB) + j f32 (64KB)
#define CH_BYTES_PER_SC ((size_t)425984)

// ---------------- helpers ----------------
static __device__ __forceinline__ float bf2f(u16 u){
  union { uint32_t i; float f; } v; v.i = ((uint32_t)u) << 16; return v.f;
}
static __device__ __forceinline__ u16 f2bf(float f){
  union { float f; uint32_t u; } v; v.f = f;
  uint32_t r = v.u + 0x7fffu + ((v.u >> 16) & 1u);
  return (u16)(r >> 16);
}
static __device__ __forceinline__ float sigmoid_f(float x){
  return 1.f / (1.f + __expf(-x));
}
static __device__ __forceinline__ float tanh_f(float x){
  x = fminf(15.f, fmaxf(-15.f, x));
  float e = __expf(2.f * x);
  return 1.f - 2.f / (e + 1.f);
}
// Exchange protocol: each u64 = {tag:32 | h_col_odd:16 | h_col_even:16}.
// One relaxed agent-scope atomic per unit: data+validity arrive atomically, so
// no flags, no producer drain, no barrier. Consumers poll tag == T.
// r7: buffer is PAIR-MAJOR so poll loads are coalesced (128B bursts), not
// 64-way 8B scatter (r6's regression).
static __device__ __forceinline__ u64 agld64(const u64* p){
  return __hip_atomic_load(p, __ATOMIC_RELAXED, __HIP_MEMORY_SCOPE_AGENT);
}
static __device__ __forceinline__ void agst64(u64* p, u64 v){
  __hip_atomic_store(p, v, __ATOMIC_RELAXED, __HIP_MEMORY_SCOPE_AGENT);
}

// ---------------- K0: weight transpose/convert (hi/lo split for GEMM weights) ----------------
__global__ void k_prep(const float* __restrict__ Wh, const float* __restrict__ Wx,
                       const float* __restrict__ Wef1, const float* __restrict__ Wef3,
                       u16* __restrict__ WhT,
                       u16* __restrict__ WxTh, u16* __restrict__ WxTl,
                       u16* __restrict__ Wef1h, u16* __restrict__ Wef1l,
                       u16* __restrict__ Wef3h, u16* __restrict__ Wef3l){
  int idx = blockIdx.x*256 + threadIdx.x;
  if (idx < 262144){ int n = idx>>8, k = idx&255; WhT[idx] = f2bf(Wh[k*1024+n]); return; }
  idx -= 262144;
  if (idx < 131072){
    int n = idx>>7, k = idx&127; float w = Wx[k*1024+n];
    u16 h = f2bf(w); WxTh[idx] = h; WxTl[idx] = f2bf(w - bf2f(h)); return;
  }
  idx -= 131072;
  if (idx < 16384){
    int n = idx>>7, k = idx&127; float w = Wef1[k*128+n];
    u16 h = f2bf(w); Wef1h[idx] = h; Wef1l[idx] = f2bf(w - bf2f(h)); return;
  }
  idx -= 16384;
  if (idx < 32768){
    int n = idx>>7, k = idx&127; float w = Wef3[k*256+n];
    u16 h = f2bf(w); Wef3h[idx] = h; Wef3l[idx] = f2bf(w - bf2f(h)); return;
  }
}

// seed hX4 buffer[3] with h0, tag 0  (pair-major: [p][r])
__global__ void k_seed(const float* __restrict__ h0, u64* __restrict__ hX4){
  int idx = blockIdx.x*256 + threadIdx.x;   // 0..8191
  int gr = idx >> 7, p = idx & 127;
  u16 he = f2bf(h0[(size_t)gr*256 + 2*p]);
  u16 ho = f2bf(h0[(size_t)gr*256 + 2*p + 1]);
  int g = gr >> 4, r = gr & 15;
  hX4[(size_t)(3*4 + g)*2048 + p*16 + r] = (u64)he | ((u64)ho << 16);  // tag 0
}

// ---------------- K1: embedding (chunked): rows m = sc*64 + b, hi/lo outputs ----------------
__global__ __launch_bounds__(256) void k_embed(
    const float* __restrict__ event, const float* __restrict__ vc, const float* __restrict__ vn,
    const float* __restrict__ Ve, const float* __restrict__ Vc, const float* __restrict__ Vn,
    u16* __restrict__ sHi, u16* __restrict__ sLo,
    u16* __restrict__ xHi, u16* __restrict__ xLo, int c0){
  __shared__ float VeL[64*128];
  __shared__ float VcL[32*128];
  __shared__ float VnL[16*128];
  __shared__ float evL[16*64];
  __shared__ float vcL[16*32];
  __shared__ float vnL[16*16];
  const int tid = threadIdx.x;
  const int sc = blockIdx.x >> 2;
  const int b0 = (blockIdx.x & 3) * 16;
  const int ss = c0 + sc;
  for (int i = tid; i < 64*128; i += 256) VeL[i] = Ve[i];
  for (int i = tid; i < 32*128; i += 256) VcL[i] = Vc[i];
  for (int i = tid; i < 16*128; i += 256) VnL[i] = Vn[i];
  for (int i = tid; i < 16*64; i += 256)
    evL[i] = event[((size_t)(b0 + (i>>6))*4096 + ss)*64 + (i&63)];
  for (int i = tid; i < 16*32; i += 256)
    vcL[i] = vc[((size_t)(b0 + (i>>5))*4096 + ss)*32 + (i&31)];
  for (int i = tid; i < 16*16; i += 256)
    vnL[i] = vn[((size_t)(b0 + (i>>4))*4096 + ss)*16 + (i&15)];
  __syncthreads();
  const int n = tid & 127, half = tid >> 7;
  for (int r = half; r < 16; r += 2){
    float sd = 0.f, cd = 0.f, nd = 0.f;
    #pragma unroll 8
    for (int k = 0; k < 64; ++k) sd = fmaf(evL[r*64+k], VeL[k*128+n], sd);
    #pragma unroll 8
    for (int k = 0; k < 32; ++k) cd = fmaf(vcL[r*32+k], VcL[k*128+n], cd);
    #pragma unroll 8
    for (int k = 0; k < 16; ++k) nd = fmaf(vnL[r*16+k], VnL[k*128+n], nd);
    float x = sd + 2.f*(cd + tanh_f(nd));
    size_t o = ((size_t)sc*64 + b0 + r)*128 + n;
    u16 sh = f2bf(sd); sHi[o] = sh; sLo[o] = f2bf(sd - bf2f(sh));
    u16 xh = f2bf(x);  xHi[o] = xh; xLo[o] = f2bf(x  - bf2f(xh));
  }
}

// ---------------- K2: split-bf16 ("bf16x3") MFMA GEMM, K=128, act+bias epilogue ----------------
// OUTKIND 0: f32 C[m][N]   1: f32 xw gate-interleaved [m][hid][gate]   2: hi/lo bf16 planes [m][N]
template<int ACT, int OUTKIND, int NTILES>
__global__ __launch_bounds__(256) void k_gemm(
    const u16* __restrict__ Ahi, const u16* __restrict__ Alo,
    const u16* __restrict__ BTh, const u16* __restrict__ BTl,
    const float* __restrict__ bias,
    float* __restrict__ CoutF, u16* __restrict__ CoutHi, u16* __restrict__ CoutLo){
  __shared__ u16 aLh[4][16*136];
  __shared__ u16 aLl[4][16*136];
  const int tid = threadIdx.x, lane = tid & 63, w = tid >> 6;
  const int c15 = lane & 15, q4 = lane >> 4;
  const size_t mbase = (size_t)blockIdx.x*64 + (size_t)w*16;
  const u16* Aph = Ahi + mbase*128;
  const u16* Apl = Alo + mbase*128;
  #pragma unroll
  for (int i = 0; i < 4; ++i){
    int row = q4 + i*4;
    *(bf16x8*)(&aLh[w][row*136 + c15*8]) = *(const bf16x8*)(Aph + row*128 + c15*8);
    *(bf16x8*)(&aLl[w][row*136 + c15*8]) = *(const bf16x8*)(Apl + row*128 + c15*8);
  }
  __syncthreads();
  bf16x8 ah[4], al[4];
  #pragma unroll
  for (int q = 0; q < 4; ++q){
    ah[q] = *(const bf16x8*)(&aLh[w][c15*136 + q*32 + q4*8]);
    al[q] = *(const bf16x8*)(&aLl[w][c15*136 + q*32 + q4*8]);
  }
  const u16* Bph = BTh + c15*128 + q4*8;
  const u16* Bpl = BTl + c15*128 + q4*8;

  bf16x8 bh[4], bl[4], bhn[4], bln[4];
  #pragma unroll
  for (int q = 0; q < 4; ++q){ bh[q] = *(const bf16x8*)(Bph + q*32); bl[q] = *(const bf16x8*)(Bpl + q*32); }

  for (int nt = 0; nt < NTILES; ++nt){
    if (nt + 1 < NTILES){
      #pragma unroll
      for (int q = 0; q < 4; ++q){
        bhn[q] = *(const bf16x8*)(Bph + (nt+1)*2048 + q*32);
        bln[q] = *(const bf16x8*)(Bpl + (nt+1)*2048 + q*32);
      }
    }
    f32x4 acc = (f32x4){0.f,0.f,0.f,0.f};
    #pragma unroll
    for (int q = 0; q < 4; ++q){
      acc = __builtin_amdgcn_mfma_f32_16x16x32_bf16(al[q], bh[q], acc, 0, 0, 0);
      acc = __builtin_amdgcn_mfma_f32_16x16x32_bf16(ah[q], bl[q], acc, 0, 0, 0);
      acc = __builtin_amdgcn_mfma_f32_16x16x32_bf16(ah[q], bh[q], acc, 0, 0, 0);
    }
    const int n = nt*16 + c15;
    const float bv = bias[n];
    #pragma unroll
    for (int i = 0; i < 4; ++i){
      float v = acc[i] + bv;
      if (ACT == 1) v = tanh_f(v);
      else if (ACT == 2) v = sigmoid_f(v);
      const size_t m = mbase + q4*4 + i;
      if (OUTKIND == 0){
        CoutF[m*(size_t)(NTILES*16) + n] = v;
      } else if (OUTKIND == 1){
        CoutF[m*1024 + (size_t)(n & 255)*4 + (size_t)(n >> 8)] = v;
      } else {
        size_t o = m*(size_t)(NTILES*16) + n;
        u16 hh = f2bf(v); CoutHi[o] = hh; CoutLo[o] = f2bf(v - bf2f(hh));
      }
    }
    #pragma unroll
    for (int q = 0; q < 4; ++q){ bh[q] = bhn[q]; bl[q] = bln[q]; }
  }
}

// ---------------- K3: the scan (chunked, tagged-u64 exchange, no barriers) ----------------
// 16 WGs = 4 batch-groups x 4 N-slots; each wave owns a 16x16 h tile.
// Pair-major exchange buffer: poll loads are 128B-coalesced bursts.
__global__ __launch_bounds__(256, 1) void k_scan(
    const u16* __restrict__ WhT, const float* __restrict__ xwG, const float* __restrict__ jG,
    const float* __restrict__ Wc, const float* __restrict__ h0, const float* __restrict__ c0in,
    const float* __restrict__ Wlin, const float* __restrict__ blin,
    u64* __restrict__ hX4, float* __restrict__ stateF,
    float* __restrict__ out, int T0, int SC, int FINAL)
{
  const int tid  = threadIdx.x;
  const int lane = tid & 63;
  const int w    = tid >> 6;
  const int g    = blockIdx.x & 3;
  const int s    = blockIdx.x >> 2;
  const int c15  = lane & 15;
  const int q4   = lane >> 4;
  const int ghid = s*64 + w*16 + c15;
  const int FIRST = (T0 == 0);

  // Wh fragments for this wave's 16 cols x 4 gates (128 VGPRs)
  bf16x8 Bf[4][8];
  {
    const u16* bp = WhT + (size_t)ghid*256 + q4*8;
    #pragma unroll
    for (int gt = 0; gt < 4; ++gt)
      #pragma unroll
      for (int q = 0; q < 8; ++q)
        Bf[gt][q] = *(const bf16x8*)(bp + (size_t)gt*65536 + q*32);
  }

  float creg[4], hreg[4];
  #pragma unroll
  for (int i = 0; i < 4; ++i){
    int r = q4*4 + i;
    if (FIRST){
      creg[i] = c0in[(size_t)(g*16 + r)*256 + ghid];
      hreg[i] = h0[(size_t)(g*16 + r)*256 + ghid];
    } else {
      creg[i] = stateF[(size_t)(g*16 + r)*256 + ghid];
      hreg[i] = stateF[16384 + (size_t)(g*16 + r)*256 + ghid];
    }
  }
  const float wc0 = Wc[ghid], wc1 = Wc[256 + ghid], wc2 = Wc[512 + ghid];

  const int P = s*32 + w*8 + (c15 >> 1);   // col-pair index this lane stores

  for (int t = 0; t < SC; ++t){
    const unsigned T = (unsigned)(T0 + t);
    const int rb = (int)((T + 3) & 3);     // read buffer: (T-1) mod 4
    const int wb = (int)(T & 3);           // write buffer: T mod 4

    // xw/j for this step: plain cached loads, latency hidden behind the poll
    f32x4 xq[4]; float jv[4];
    {
      const float* xwp = xwG + ((size_t)t*64 + g*16)*1024 + (size_t)ghid*4;
      const float* jp  = jG  + ((size_t)t*64 + g*16)*256 + ghid;
      #pragma unroll
      for (int i = 0; i < 4; ++i){
        int r = q4*4 + i;
        xq[i] = *(const f32x4*)(xwp + (size_t)r*1024);
        jv[i] = jp[(size_t)r*256];
      }
    }

    // ---- poll A-operand row c15 (32 tagged u64s = 256 h values), coalesced ----
    const u64* hr = hX4 + (size_t)(rb*4 + g)*2048 + c15;
    u64 d[8][4];
    for (;;){
      #pragma unroll
      for (int q = 0; q < 8; ++q)
        #pragma unroll
        for (int jj = 0; jj < 4; ++jj)
          d[q][jj] = agld64(hr + (q*16 + q4*4 + jj)*16);
      bool ok = true;
      #pragma unroll
      for (int q = 0; q < 8; ++q)
        #pragma unroll
        for (int jj = 0; jj < 4; ++jj)
          ok &= ((u32)(d[q][jj] >> 32) == T);
      if (ok) break;
    }
    bf16x8 Af[8];
    #pragma unroll
    for (int q = 0; q < 8; ++q){
      union { u32 dd[4]; bf16x8 v; } cv;
      #pragma unroll
      for (int jj = 0; jj < 4; ++jj) cv.dd[jj] = (u32)d[q][jj];
      Af[q] = cv.v;
    }

    // ---- MFMA: gates(16x16 per gate) = h(16x256) @ Wh_tile ----
    f32x4 acc[4];
    #pragma unroll
    for (int gt = 0; gt < 4; ++gt) acc[gt] = (f32x4){0.f,0.f,0.f,0.f};
    #pragma unroll
    for (int q = 0; q < 8; ++q)
      #pragma unroll
      for (int gt = 0; gt < 4; ++gt)
        acc[gt] = __builtin_amdgcn_mfma_f32_16x16x32_bf16(Af[q], Bf[gt][q], acc[gt], 0, 0, 0);

    // ---- elementwise LSTM update (4 rows x col c15) ----
    u16 hb[4];
    #pragma unroll
    for (int i = 0; i < 4; ++i){
      float ip = acc[0][i] + xq[i][0] + creg[i]*wc0;
      float fp = acc[1][i] + xq[i][1] + creg[i]*wc1;
      float gp = acc[2][i] + xq[i][2];
      float op = acc[3][i] + xq[i][3] + creg[i]*wc2;
      float it = sigmoid_f(ip);
      float ft = sigmoid_f(fp);
      float gt = tanh_f(gp);
      float ot = sigmoid_f(op);
      float chat = ft*creg[i] + it*gt;
      float cn = creg[i] + jv[i]*(chat - creg[i]);
      float hhat = ot*tanh_f(chat);
      float hn = hreg[i] + jv[i]*(hhat - hreg[i]);
      creg[i] = cn; hreg[i] = hn;
      hb[i] = f2bf(hn);
    }

    // ---- pack col-pairs via lane^1 exchange, tagged stores (pair-major) ----
    u32 a = (u32)hb[0] | ((u32)hb[1] << 16);
    u32 b = (u32)hb[2] | ((u32)hb[3] << 16);
    u32 pa = (u32)__shfl_xor((int)a, 1, 64);
    u32 pb = (u32)__shfl_xor((int)b, 1, 64);
    u64* hw = hX4 + (size_t)(wb*4 + g)*2048 + (size_t)P*16;
    const u64 tag = ((u64)(T + 1)) << 32;
    if ((lane & 1) == 0){
      u64 v0 = tag | (u64)((a & 0xffffu) | ((pa & 0xffffu) << 16));
      u64 v1 = tag | (u64)((a >> 16) | (pa & 0xffff0000u));
      agst64(hw + q4*4 + 0, v0);
      agst64(hw + q4*4 + 1, v1);
    } else {
      u64 v2 = tag | (u64)((pb & 0xffffu) | ((b & 0xffffu) << 16));
      u64 v3 = tag | (u64)((pb >> 16) | (b & 0xffff0000u));
      agst64(hw + q4*4 + 2, v2);
      agst64(hw + q4*4 + 3, v3);
    }
  }

  // persist f32 state for next chunk (same wave reads it back next launch)
  if (!FINAL){
    #pragma unroll
    for (int i = 0; i < 4; ++i){
      int r = q4*4 + i;
      stateF[(size_t)(g*16 + r)*256 + ghid] = creg[i];
      stateF[16384 + (size_t)(g*16 + r)*256 + ghid] = hreg[i];
    }
  }

  // epilogue on final chunk: out = h_T @ Wlin + blin  (slot-0 WG per group)
  if (FINAL && s == 0){
    __shared__ float hF[16*256];
    const unsigned tgt = (unsigned)NS;     // h_T carries tag NS in buffer 3
    for (int idx = tid; idx < 2048; idx += 256){
      int r = idx >> 7, p = idx & 127;
      const u64* ap = hX4 + (size_t)(3*4 + g)*2048 + p*16 + r;
      u64 v;
      do { v = agld64(ap); } while ((u32)(v >> 32) != tgt);
      hF[r*256 + 2*p]     = bf2f((u16)v);
      hF[r*256 + 2*p + 1] = bf2f((u16)(v >> 16));
    }
    __syncthreads();
    for (int idx = tid; idx < 1024; idx += 256){
      int r = idx >> 6, dcol = idx & 63;
      float aacc = blin[dcol];
      for (int k = 0; k < 256; ++k)
        aacc = fmaf(hF[r*256 + k], Wlin[k*64 + dcol], aacc);
      out[(size_t)(g*16 + r)*64 + dcol] = aacc;
    }
  }
}

// ---------------- host ----------------
extern "C" void kernel_launch(void* const* d_in, const int* in_sizes, int n_in,
                              void* d_out, int out_size, void* d_ws, size_t ws_size,
                              hipStream_t stream)
{
  (void)in_sizes; (void)n_in;
  const float* event = (const float*)d_in[0];
  const float* vc    = (const float*)d_in[2];
  const float* vn    = (const float*)d_in[3];
  const float* h0    = (const float*)d_in[4];
  const float* c0v   = (const float*)d_in[5];
  const float* Wx    = (const float*)d_in[6];
  const float* Wh    = (const float*)d_in[7];
  const float* Wc    = (const float*)d_in[8];
  const float* bias  = (const float*)d_in[9];
  const float* Ve    = (const float*)d_in[10];
  const float* Vc    = (const float*)d_in[11];
  const float* Vn    = (const float*)d_in[12];
  const float* Wlin  = (const float*)d_in[13];
  const float* blin  = (const float*)d_in[14];
  const float* Wef1  = (const float*)d_in[15];
  const float* bef1  = (const float*)d_in[16];
  const float* Wef3  = (const float*)d_in[17];
  const float* bef3  = (const float*)d_in[18];

  int SC = 0;
  const int cands[9] = {4096, 2048, 1024, 512, 256, 128, 64, 32, 16};
  for (int i = 0; i < 9; ++i){
    if (OFF_CH + (size_t)cands[i]*CH_BYTES_PER_SC <= ws_size){ SC = cands[i]; break; }
  }
  if (SC == 0){
    hipMemsetAsync(d_out, 0, (size_t)out_size*sizeof(float), stream);
    return;
  }
  const int C = NS / SC;

  char* ws = (char*)d_ws;
  u64*   hX4    = (u64*)(ws + OFF_HX4);
  float* stateF = (float*)(ws + OFF_STATE);
  u16* WhT   = (u16*)(ws + OFF_WHT);
  u16* WxTh  = (u16*)(ws + OFF_WXTH);
  u16* WxTl  = (u16*)(ws + OFF_WXTL);
  u16* Wef1h = (u16*)(ws + OFF_WEF1H);
  u16* Wef1l = (u16*)(ws + OFF_WEF1L);
  u16* Wef3h = (u16*)(ws + OFF_WEF3H);
  u16* Wef3l = (u16*)(ws + OFF_WEF3L);
  char* ch = ws + OFF_CH;
  u16* sHi  = (u16*)ch;
  u16* sLo  = (u16*)(ch + (size_t)SC*16384);
  u16* xHi  = (u16*)(ch + (size_t)SC*32768);
  u16* xLo  = (u16*)(ch + (size_t)SC*49152);
  u16* e1Hi = (u16*)(ch + (size_t)SC*65536);
  u16* e1Lo = (u16*)(ch + (size_t)SC*81920);
  float* xwG = (float*)(ch + (size_t)SC*98304);
  float* jG  = (float*)(ch + (size_t)SC*360448);

  k_prep<<<1728, 256, 0, stream>>>(Wh, Wx, Wef1, Wef3, WhT, WxTh, WxTl,
                                   Wef1h, Wef1l, Wef3h, Wef3l);
  k_seed<<<32, 256, 0, stream>>>(h0, hX4);

  for (int c = 0; c < C; ++c){
    const int c0 = c * SC;
    k_embed<<<SC*4, 256, 0, stream>>>(event, vc, vn, Ve, Vc, Vn, sHi, sLo, xHi, xLo, c0);
    k_gemm<0,1,64><<<SC, 256, 0, stream>>>(xHi, xLo, WxTh, WxTl, bias, xwG, nullptr, nullptr);
    k_gemm<1,2,8><<<SC, 256, 0, stream>>>(sHi, sLo, Wef1h, Wef1l, bef1, nullptr, e1Hi, e1Lo);
    k_gemm<2,0,16><<<SC, 256, 0, stream>>>(e1Hi, e1Lo, Wef3h, Wef3l, bef3, jG, nullptr, nullptr);
    k_scan<<<16, 256, 0, stream>>>(WhT, xwG, jG, Wc, h0, c0v, Wlin, blin,
                                   hX4, stateF, (float*)d_out, c0, SC, (c == C-1) ? 1 : 0);
  }
}

// Round 8
// 15621.303 us; speedup vs baseline: 1.8996x; 1.2461x over previous
//
#include <hip/hip_runtime.h>
#include <cstdint>
#include <cstddef>

typedef __attribute__((ext_vector_type(8))) short bf16x8;
typedef __attribute__((ext_vector_type(4))) float f32x4;
typedef uint16_t u16;
typedef uint32_t u32;
typedef uint64_t u64;

#define NS 4096

// ---------------- fixed workspace layout (bytes) ----------------
// hX4: fast tagged exchange (same-XCD L2 path), pair-major [4 bufs][4 g][128 p][16 r] u64
// hXM: MALL mirror of the same data (agent-scope fallback + epilogue source)
#define OFF_HX4    ((size_t)0)                        // 256 KB
#define OFF_HXM    ((size_t)262144)                   // 256 KB
#define OFF_STATE  ((size_t)524288)                   // 128 KB: c then h, f32 [64][256]
#define OFF_WHT    ((size_t)655360)                   // 512 KB
#define OFF_WXTH   (OFF_WHT   + (size_t)524288)
#define OFF_WXTL   (OFF_WXTH  + (size_t)262144)
#define OFF_WEF1H  (OFF_WXTL  + (size_t)262144)
#define OFF_WEF1L  (OFF_WEF1H + (size_t)32768)
#define OFF_WEF3H  (OFF_WEF1L + (size_t)32768)
#define OFF_WEF3L  (OFF_WEF3H + (size_t)65536)
#define OFF_CH     ((size_t)2*1024*1024)              // chunk region
// per-step: s hi/lo + x hi/lo + e1 hi/lo (6x16KB) + xw f32 (256KB) + j f32 (64KB)
#define CH_BYTES_PER_SC ((size_t)425984)

// ---------------- helpers ----------------
static __device__ __forceinline__ float bf2f(u16 u){
  union { uint32_t i; float f; } v; v.i = ((uint32_t)u) << 16; return v.f;
}
static __device__ __forceinline__ u16 f2bf(float f){
  union { float f; uint32_t u; } v; v.f = f;
  uint32_t r = v.u + 0x7fffu + ((v.u >> 16) & 1u);
  return (u16)(r >> 16);
}
static __device__ __forceinline__ float sigmoid_f(float x){
  return 1.f / (1.f + __expf(-x));
}
static __device__ __forceinline__ float tanh_f(float x){
  x = fminf(15.f, fmaxf(-15.f, x));
  float e = __expf(2.f * x);
  return 1.f - 2.f / (e + 1.f);
}
// MALL-path (agent-scope) atomics: bypass L1+L2 to the device coherence point.
static __device__ __forceinline__ u64 agld64(const u64* p){
  return __hip_atomic_load(p, __ATOMIC_RELAXED, __HIP_MEMORY_SCOPE_AGENT);
}
static __device__ __forceinline__ void agst64(u64* p, u64 v){
  __hip_atomic_store(p, v, __ATOMIC_RELAXED, __HIP_MEMORY_SCOPE_AGENT);
}

// ---------------- K0: weight transpose/convert (hi/lo split for GEMM weights) ----------------
__global__ void k_prep(const float* __restrict__ Wh, const float* __restrict__ Wx,
                       const float* __restrict__ Wef1, const float* __restrict__ Wef3,
                       u16* __restrict__ WhT,
                       u16* __restrict__ WxTh, u16* __restrict__ WxTl,
                       u16* __restrict__ Wef1h, u16* __restrict__ Wef1l,
                       u16* __restrict__ Wef3h, u16* __restrict__ Wef3l){
  int idx = blockIdx.x*256 + threadIdx.x;
  if (idx < 262144){ int n = idx>>8, k = idx&255; WhT[idx] = f2bf(Wh[k*1024+n]); return; }
  idx -= 262144;
  if (idx < 131072){
    int n = idx>>7, k = idx&127; float w = Wx[k*1024+n];
    u16 h = f2bf(w); WxTh[idx] = h; WxTl[idx] = f2bf(w - bf2f(h)); return;
  }
  idx -= 131072;
  if (idx < 16384){
    int n = idx>>7, k = idx&127; float w = Wef1[k*128+n];
    u16 h = f2bf(w); Wef1h[idx] = h; Wef1l[idx] = f2bf(w - bf2f(h)); return;
  }
  idx -= 16384;
  if (idx < 32768){
    int n = idx>>7, k = idx&127; float w = Wef3[k*256+n];
    u16 h = f2bf(w); Wef3h[idx] = h; Wef3l[idx] = f2bf(w - bf2f(h)); return;
  }
}

// seed BOTH exchange buffers, buffer[3], tag 0 (pair-major [p][r])
__global__ void k_seed(const float* __restrict__ h0, u64* __restrict__ hX4,
                       u64* __restrict__ hXM){
  int idx = blockIdx.x*256 + threadIdx.x;   // 0..8191
  int gr = idx >> 7, p = idx & 127;
  u16 he = f2bf(h0[(size_t)gr*256 + 2*p]);
  u16 ho = f2bf(h0[(size_t)gr*256 + 2*p + 1]);
  int g = gr >> 4, r = gr & 15;
  u64 v = (u64)he | ((u64)ho << 16);        // tag 0
  size_t o = (size_t)(3*4 + g)*2048 + p*16 + r;
  hX4[o] = v; hXM[o] = v;
}

// ---------------- K1: embedding (chunked): rows m = sc*64 + b, hi/lo outputs ----------------
__global__ __launch_bounds__(256) void k_embed(
    const float* __restrict__ event, const float* __restrict__ vc, const float* __restrict__ vn,
    const float* __restrict__ Ve, const float* __restrict__ Vc, const float* __restrict__ Vn,
    u16* __restrict__ sHi, u16* __restrict__ sLo,
    u16* __restrict__ xHi, u16* __restrict__ xLo, int c0){
  __shared__ float VeL[64*128];
  __shared__ float VcL[32*128];
  __shared__ float VnL[16*128];
  __shared__ float evL[16*64];
  __shared__ float vcL[16*32];
  __shared__ float vnL[16*16];
  const int tid = threadIdx.x;
  const int sc = blockIdx.x >> 2;
  const int b0 = (blockIdx.x & 3) * 16;
  const int ss = c0 + sc;
  for (int i = tid; i < 64*128; i += 256) VeL[i] = Ve[i];
  for (int i = tid; i < 32*128; i += 256) VcL[i] = Vc[i];
  for (int i = tid; i < 16*128; i += 256) VnL[i] = Vn[i];
  for (int i = tid; i < 16*64; i += 256)
    evL[i] = event[((size_t)(b0 + (i>>6))*4096 + ss)*64 + (i&63)];
  for (int i = tid; i < 16*32; i += 256)
    vcL[i] = vc[((size_t)(b0 + (i>>5))*4096 + ss)*32 + (i&31)];
  for (int i = tid; i < 16*16; i += 256)
    vnL[i] = vn[((size_t)(b0 + (i>>4))*4096 + ss)*16 + (i&15)];
  __syncthreads();
  const int n = tid & 127, half = tid >> 7;
  for (int r = half; r < 16; r += 2){
    float sd = 0.f, cd = 0.f, nd = 0.f;
    #pragma unroll 8
    for (int k = 0; k < 64; ++k) sd = fmaf(evL[r*64+k], VeL[k*128+n], sd);
    #pragma unroll 8
    for (int k = 0; k < 32; ++k) cd = fmaf(vcL[r*32+k], VcL[k*128+n], cd);
    #pragma unroll 8
    for (int k = 0; k < 16; ++k) nd = fmaf(vnL[r*16+k], VnL[k*128+n], nd);
    float x = sd + 2.f*(cd + tanh_f(nd));
    size_t o = ((size_t)sc*64 + b0 + r)*128 + n;
    u16 sh = f2bf(sd); sHi[o] = sh; sLo[o] = f2bf(sd - bf2f(sh));
    u16 xh = f2bf(x);  xHi[o] = xh; xLo[o] = f2bf(x  - bf2f(xh));
  }
}

// ---------------- K2: split-bf16 ("bf16x3") MFMA GEMM, K=128, act+bias epilogue ----------------
// OUTKIND 0: f32 C[m][N]   1: f32 xw gate-interleaved [m][hid][gate]   2: hi/lo bf16 planes [m][N]
template<int ACT, int OUTKIND, int NTILES>
__global__ __launch_bounds__(256) void k_gemm(
    const u16* __restrict__ Ahi, const u16* __restrict__ Alo,
    const u16* __restrict__ BTh, const u16* __restrict__ BTl,
    const float* __restrict__ bias,
    float* __restrict__ CoutF, u16* __restrict__ CoutHi, u16* __restrict__ CoutLo){
  __shared__ u16 aLh[4][16*136];
  __shared__ u16 aLl[4][16*136];
  const int tid = threadIdx.x, lane = tid & 63, w = tid >> 6;
  const int c15 = lane & 15, q4 = lane >> 4;
  const size_t mbase = (size_t)blockIdx.x*64 + (size_t)w*16;
  const u16* Aph = Ahi + mbase*128;
  const u16* Apl = Alo + mbase*128;
  #pragma unroll
  for (int i = 0; i < 4; ++i){
    int row = q4 + i*4;
    *(bf16x8*)(&aLh[w][row*136 + c15*8]) = *(const bf16x8*)(Aph + row*128 + c15*8);
    *(bf16x8*)(&aLl[w][row*136 + c15*8]) = *(const bf16x8*)(Apl + row*128 + c15*8);
  }
  __syncthreads();
  bf16x8 ah[4], al[4];
  #pragma unroll
  for (int q = 0; q < 4; ++q){
    ah[q] = *(const bf16x8*)(&aLh[w][c15*136 + q*32 + q4*8]);
    al[q] = *(const bf16x8*)(&aLl[w][c15*136 + q*32 + q4*8]);
  }
  const u16* Bph = BTh + c15*128 + q4*8;
  const u16* Bpl = BTl + c15*128 + q4*8;

  bf16x8 bh[4], bl[4], bhn[4], bln[4];
  #pragma unroll
  for (int q = 0; q < 4; ++q){ bh[q] = *(const bf16x8*)(Bph + q*32); bl[q] = *(const bf16x8*)(Bpl + q*32); }

  for (int nt = 0; nt < NTILES; ++nt){
    if (nt + 1 < NTILES){
      #pragma unroll
      for (int q = 0; q < 4; ++q){
        bhn[q] = *(const bf16x8*)(Bph + (nt+1)*2048 + q*32);
        bln[q] = *(const bf16x8*)(Bpl + (nt+1)*2048 + q*32);
      }
    }
    f32x4 acc = (f32x4){0.f,0.f,0.f,0.f};
    #pragma unroll
    for (int q = 0; q < 4; ++q){
      acc = __builtin_amdgcn_mfma_f32_16x16x32_bf16(al[q], bh[q], acc, 0, 0, 0);
      acc = __builtin_amdgcn_mfma_f32_16x16x32_bf16(ah[q], bl[q], acc, 0, 0, 0);
      acc = __builtin_amdgcn_mfma_f32_16x16x32_bf16(ah[q], bh[q], acc, 0, 0, 0);
    }
    const int n = nt*16 + c15;
    const float bv = bias[n];
    #pragma unroll
    for (int i = 0; i < 4; ++i){
      float v = acc[i] + bv;
      if (ACT == 1) v = tanh_f(v);
      else if (ACT == 2) v = sigmoid_f(v);
      const size_t m = mbase + q4*4 + i;
      if (OUTKIND == 0){
        CoutF[m*(size_t)(NTILES*16) + n] = v;
      } else if (OUTKIND == 1){
        CoutF[m*1024 + (size_t)(n & 255)*4 + (size_t)(n >> 8)] = v;
      } else {
        size_t o = m*(size_t)(NTILES*16) + n;
        u16 hh = f2bf(v); CoutHi[o] = hh; CoutLo[o] = f2bf(v - bf2f(hh));
      }
    }
    #pragma unroll
    for (int q = 0; q < 4; ++q){ bh[q] = bhn[q]; bl[q] = bln[q]; }
  }
}

// ---------------- K3: the scan — same-XCD L2 exchange with MALL fallback ----------------
// 32 WGs launched; role (g,s) = (blockIdx&7, blockIdx>>3), g>=4 exits.
// Under round-robin XCD dispatch a group's 4 slots co-locate on one XCD ->
// plain stores + nt loads are coherent through that L2 (~200cyc). If placement
// or cache semantics differ, per-lane fastOK flips after 512 tries and that
// lane uses the MALL mirror (correct, r7-speed). Roles come from blockIdx, so
// placement never affects correctness.
__global__ __launch_bounds__(256, 1) void k_scan(
    const u16* __restrict__ WhT, const float* __restrict__ xwG, const float* __restrict__ jG,
    const float* __restrict__ Wc, const float* __restrict__ h0, const float* __restrict__ c0in,
    const float* __restrict__ Wlin, const float* __restrict__ blin,
    u64* __restrict__ hX4, u64* __restrict__ hXM, float* __restrict__ stateF,
    float* __restrict__ out, int T0, int SC, int FINAL)
{
  const int xcd  = blockIdx.x & 7;
  const int ring = blockIdx.x >> 3;
  if (xcd >= 4) return;
  const int g = xcd, s = ring;

  const int tid  = threadIdx.x;
  const int lane = tid & 63;
  const int w    = tid >> 6;
  const int c15  = lane & 15;
  const int q4   = lane >> 4;
  const int ghid = s*64 + w*16 + c15;
  const int FIRST = (T0 == 0);

  // Wh fragments for this wave's 16 cols x 4 gates (128 VGPRs)
  bf16x8 Bf[4][8];
  {
    const u16* bp = WhT + (size_t)ghid*256 + q4*8;
    #pragma unroll
    for (int gt = 0; gt < 4; ++gt)
      #pragma unroll
      for (int q = 0; q < 8; ++q)
        Bf[gt][q] = *(const bf16x8*)(bp + (size_t)gt*65536 + q*32);
  }

  float creg[4], hreg[4];
  #pragma unroll
  for (int i = 0; i < 4; ++i){
    int r = q4*4 + i;
    if (FIRST){
      creg[i] = c0in[(size_t)(g*16 + r)*256 + ghid];
      hreg[i] = h0[(size_t)(g*16 + r)*256 + ghid];
    } else {
      creg[i] = stateF[(size_t)(g*16 + r)*256 + ghid];
      hreg[i] = stateF[16384 + (size_t)(g*16 + r)*256 + ghid];
    }
  }
  const float wc0 = Wc[ghid], wc1 = Wc[256 + ghid], wc2 = Wc[512 + ghid];

  const int P = s*32 + w*8 + (c15 >> 1);   // col-pair index this lane stores

  // xw/j register prefetch (one step ahead; ping-pong arrays, no copies)
  f32x4 xqA[4], xqB[4]; float jvA[4], jvB[4];
  auto ldxw = [&](int tn, f32x4* xq, float* jv){
    const float* xwp = xwG + ((size_t)tn*64 + g*16)*1024 + (size_t)ghid*4;
    const float* jp  = jG  + ((size_t)tn*64 + g*16)*256 + ghid;
    #pragma unroll
    for (int i = 0; i < 4; ++i){
      int r = q4*4 + i;
      xq[i] = *(const f32x4*)(xwp + (size_t)r*1024);
      jv[i] = jp[(size_t)r*256];
    }
  };
  ldxw(0, xqA, jvA);

  bool fastOK = true;

  auto step = [&](int t, f32x4* xq, float* jv, f32x4* xqN, float* jvN){
    const unsigned T = (unsigned)(T0 + t);
    const int rb = (int)((T + 3) & 3);
    const int wb = (int)(T & 3);
    const u64* hrL = hX4 + (size_t)(rb*4 + g)*2048 + c15;
    const u64* hrM = hXM + (size_t)(rb*4 + g)*2048 + c15;

    u64 d[8][4];
    bool got = false;
    if (fastOK){
      int it = 0;
      for(;;){
        #pragma unroll
        for (int q = 0; q < 8; ++q)
          #pragma unroll
          for (int jj = 0; jj < 4; ++jj)
            d[q][jj] = __builtin_nontemporal_load(hrL + (q*16 + q4*4 + jj)*16);
        bool ok = true;
        #pragma unroll
        for (int q = 0; q < 8; ++q)
          #pragma unroll
          for (int jj = 0; jj < 4; ++jj)
            ok &= ((u32)(d[q][jj] >> 32) == T);
        if (ok){ got = true; break; }
        if (++it >= 512) break;
        asm volatile("" ::: "memory");   // force re-load next iteration
      }
      if (!got) fastOK = false;
    }
    if (!got){
      for(;;){
        #pragma unroll
        for (int q = 0; q < 8; ++q)
          #pragma unroll
          for (int jj = 0; jj < 4; ++jj)
            d[q][jj] = agld64(hrM + (q*16 + q4*4 + jj)*16);
        bool ok = true;
        #pragma unroll
        for (int q = 0; q < 8; ++q)
          #pragma unroll
          for (int jj = 0; jj < 4; ++jj)
            ok &= ((u32)(d[q][jj] >> 32) == T);
        if (ok) break;
      }
    }

    bf16x8 Af[8];
    #pragma unroll
    for (int q = 0; q < 8; ++q){
      union { u32 dd[4]; bf16x8 v; } cv;
      #pragma unroll
      for (int jj = 0; jj < 4; ++jj) cv.dd[jj] = (u32)d[q][jj];
      Af[q] = cv.v;
    }

    // issue next step's xw/j now: vmcnt in-order => by the time t+1's poll
    // succeeds these are complete; first use waits for free.
    if (t + 1 < SC) ldxw(t + 1, xqN, jvN);

    f32x4 acc[4];
    #pragma unroll
    for (int gt = 0; gt < 4; ++gt) acc[gt] = (f32x4){0.f,0.f,0.f,0.f};
    #pragma unroll
    for (int q = 0; q < 8; ++q)
      #pragma unroll
      for (int gt = 0; gt < 4; ++gt)
        acc[gt] = __builtin_amdgcn_mfma_f32_16x16x32_bf16(Af[q], Bf[gt][q], acc[gt], 0, 0, 0);

    u16 hb[4];
    #pragma unroll
    for (int i = 0; i < 4; ++i){
      float ip = acc[0][i] + xq[i][0] + creg[i]*wc0;
      float fp = acc[1][i] + xq[i][1] + creg[i]*wc1;
      float gp = acc[2][i] + xq[i][2];
      float op = acc[3][i] + xq[i][3] + creg[i]*wc2;
      float it2 = sigmoid_f(ip);
      float ft = sigmoid_f(fp);
      float gt = tanh_f(gp);
      float ot = sigmoid_f(op);
      float chat = ft*creg[i] + it2*gt;
      float cn = creg[i] + jv[i]*(chat - creg[i]);
      float hhat = ot*tanh_f(chat);
      float hn = hreg[i] + jv[i]*(hhat - hreg[i]);
      creg[i] = cn; hreg[i] = hn;
      hb[i] = f2bf(hn);
    }

    u32 a = (u32)hb[0] | ((u32)hb[1] << 16);
    u32 b = (u32)hb[2] | ((u32)hb[3] << 16);
    u32 pa = (u32)__shfl_xor((int)a, 1, 64);
    u32 pb = (u32)__shfl_xor((int)b, 1, 64);
    u64* hwL = hX4 + (size_t)(wb*4 + g)*2048 + (size_t)P*16;
    u64* hwM = hXM + (size_t)(wb*4 + g)*2048 + (size_t)P*16;
    const u64 tag = ((u64)(T + 1)) << 32;
    if ((lane & 1) == 0){
      u64 v0 = tag | (u64)((a & 0xffffu) | ((pa & 0xffffu) << 16));
      u64 v1 = tag | (u64)((a >> 16) | (pa & 0xffff0000u));
      hwL[q4*4 + 0] = v0;  hwL[q4*4 + 1] = v1;       // L2 fast path
      agst64(hwM + q4*4 + 0, v0); agst64(hwM + q4*4 + 1, v1);  // MALL mirror
    } else {
      u64 v2 = tag | (u64)((pb & 0xffffu) | ((b & 0xffffu) << 16));
      u64 v3 = tag | (u64)((pb >> 16) | (b & 0xffff0000u));
      hwL[q4*4 + 2] = v2;  hwL[q4*4 + 3] = v3;
      agst64(hwM + q4*4 + 2, v2); agst64(hwM + q4*4 + 3, v3);
    }
    asm volatile("" ::: "memory");   // keep stores inside this step
  };

  for (int t = 0; t < SC; t += 2){   // SC is always even
    step(t,     xqA, jvA, xqB, jvB);
    step(t + 1, xqB, jvB, xqA, jvA);
  }

  // persist f32 state for next chunk (kernel-boundary flush makes it visible)
  if (!FINAL){
    #pragma unroll
    for (int i = 0; i < 4; ++i){
      int r = q4*4 + i;
      stateF[(size_t)(g*16 + r)*256 + ghid] = creg[i];
      stateF[16384 + (size_t)(g*16 + r)*256 + ghid] = hreg[i];
    }
  }

  // epilogue on final chunk: out = h_T @ Wlin + blin  (slot-0 WG per group)
  // reads the MALL mirror (always coherent cross-XCD)
  if (FINAL && s == 0){
    __shared__ float hF[16*256];
    const unsigned tgt = (unsigned)NS;     // h_T carries tag NS in buffer 3
    for (int idx = tid; idx < 2048; idx += 256){
      int r = idx >> 7, p = idx & 127;
      const u64* ap = hXM + (size_t)(3*4 + g)*2048 + p*16 + r;
      u64 v;
      do { v = agld64(ap); } while ((u32)(v >> 32) != tgt);
      hF[r*256 + 2*p]     = bf2f((u16)v);
      hF[r*256 + 2*p + 1] = bf2f((u16)(v >> 16));
    }
    __syncthreads();
    for (int idx = tid; idx < 1024; idx += 256){
      int r = idx >> 6, dcol = idx & 63;
      float aacc = blin[dcol];
      for (int k = 0; k < 256; ++k)
        aacc = fmaf(hF[r*256 + k], Wlin[k*64 + dcol], aacc);
      out[(size_t)(g*16 + r)*64 + dcol] = aacc;
    }
  }
}

// ---------------- host ----------------
extern "C" void kernel_launch(void* const* d_in, const int* in_sizes, int n_in,
                              void* d_out, int out_size, void* d_ws, size_t ws_size,
                              hipStream_t stream)
{
  (void)in_sizes; (void)n_in;
  const float* event = (const float*)d_in[0];
  const float* vc    = (const float*)d_in[2];
  const float* vn    = (const float*)d_in[3];
  const float* h0    = (const float*)d_in[4];
  const float* c0v   = (const float*)d_in[5];
  const float* Wx    = (const float*)d_in[6];
  const float* Wh    = (const float*)d_in[7];
  const float* Wc    = (const float*)d_in[8];
  const float* bias  = (const float*)d_in[9];
  const float* Ve    = (const float*)d_in[10];
  const float* Vc    = (const float*)d_in[11];
  const float* Vn    = (const float*)d_in[12];
  const float* Wlin  = (const float*)d_in[13];
  const float* blin  = (const float*)d_in[14];
  const float* Wef1  = (const float*)d_in[15];
  const float* bef1  = (const float*)d_in[16];
  const float* Wef3  = (const float*)d_in[17];
  const float* bef3  = (const float*)d_in[18];

  int SC = 0;
  const int cands[9] = {4096, 2048, 1024, 512, 256, 128, 64, 32, 16};
  for (int i = 0; i < 9; ++i){
    if (OFF_CH + (size_t)cands[i]*CH_BYTES_PER_SC <= ws_size){ SC = cands[i]; break; }
  }
  if (SC == 0){
    hipMemsetAsync(d_out, 0, (size_t)out_size*sizeof(float), stream);
    return;
  }
  const int C = NS / SC;

  char* ws = (char*)d_ws;
  u64*   hX4    = (u64*)(ws + OFF_HX4);
  u64*   hXM    = (u64*)(ws + OFF_HXM);
  float* stateF = (float*)(ws + OFF_STATE);
  u16* WhT   = (u16*)(ws + OFF_WHT);
  u16* WxTh  = (u16*)(ws + OFF_WXTH);
  u16* WxTl  = (u16*)(ws + OFF_WXTL);
  u16* Wef1h = (u16*)(ws + OFF_WEF1H);
  u16* Wef1l = (u16*)(ws + OFF_WEF1L);
  u16* Wef3h = (u16*)(ws + OFF_WEF3H);
  u16* Wef3l = (u16*)(ws + OFF_WEF3L);
  char* ch = ws + OFF_CH;
  u16* sHi  = (u16*)ch;
  u16* sLo  = (u16*)(ch + (size_t)SC*16384);
  u16* xHi  = (u16*)(ch + (size_t)SC*32768);
  u16* xLo  = (u16*)(ch + (size_t)SC*49152);
  u16* e1Hi = (u16*)(ch + (size_t)SC*65536);
  u16* e1Lo = (u16*)(ch + (size_t)SC*81920);
  float* xwG = (float*)(ch + (size_t)SC*98304);
  float* jG  = (float*)(ch + (size_t)SC*360448);

  k_prep<<<1728, 256, 0, stream>>>(Wh, Wx, Wef1, Wef3, WhT, WxTh, WxTl,
                                   Wef1h, Wef1l, Wef3h, Wef3l);
  k_seed<<<32, 256, 0, stream>>>(h0, hX4, hXM);

  for (int c = 0; c < C; ++c){
    const int c0 = c * SC;
    k_embed<<<SC*4, 256, 0, stream>>>(event, vc, vn, Ve, Vc, Vn, sHi, sLo, xHi, xLo, c0);
    k_gemm<0,1,64><<<SC, 256, 0, stream>>>(xHi, xLo, WxTh, WxTl, bias, xwG, nullptr, nullptr);
    k_gemm<1,2,8><<<SC, 256, 0, stream>>>(sHi, sLo, Wef1h, Wef1l, bef1, nullptr, e1Hi, e1Lo);
    k_gemm<2,0,16><<<SC, 256, 0, stream>>>(e1Hi, e1Lo, Wef3h, Wef3l, bef3, jG, nullptr, nullptr);
    k_scan<<<32, 256, 0, stream>>>(WhT, xwG, jG, Wc, h0, c0v, Wlin, blin,
                                   hX4, hXM, stateF, (float*)d_out, c0, SC, (c == C-1) ? 1 : 0);
  }
}